// Round 1
// baseline (230.948 us; speedup 1.0000x reference)
//
#include <hip/hip_runtime.h>
#include <hip/hip_bf16.h>

// Problem constants
#define NROWS 16384          // B*T
#define FDIM  512            // K
#define GE    640            // G*E
#define EDIM  320
#define DDIM  384
#define Q_OFF 0
#define CB_OFF 12582912      // 16384*768
#define SCAL_OFF 23068672    // CB_OFF + 16384*640

// ---------------- init accumulators ----------------
__global__ void vq_init_k(float* acc) {
    int i = blockIdx.x * 256 + threadIdx.x;
    if (i < 1280) acc[i] = 0.0f;
}

// ---------------- GEMM: logits = X @ W^T + b ----------------
// X: (16384,512) row-major, W: (640,512) row-major (K contiguous both), L: (16384,640)
__global__ __launch_bounds__(256) void gemm_logits_k(
    const float* __restrict__ X, const float* __restrict__ W,
    const float* __restrict__ bias, float* __restrict__ L)
{
    __shared__ float As[32][68];   // [k][m], stride 68 floats = 272B (16B aligned)
    __shared__ float Bs[32][68];   // [k][n]

    const int tid = threadIdx.x;
    const int tm = tid >> 4;       // 0..15
    const int tn = tid & 15;       // 0..15
    const int row0 = blockIdx.x * 64;
    const int col0 = blockIdx.y * 64;

    float acc[4][4] = {};

    for (int k0 = 0; k0 < FDIM; k0 += 32) {
        #pragma unroll
        for (int it = 0; it < 2; ++it) {
            const int idx = tid + it * 256;       // 0..511
            const int r = idx >> 3;               // 0..63
            const int c = (idx & 7) << 2;         // 0,4,...,28
            const float4 av = *reinterpret_cast<const float4*>(
                X + (size_t)(row0 + r) * FDIM + k0 + c);
            As[c + 0][r] = av.x; As[c + 1][r] = av.y;
            As[c + 2][r] = av.z; As[c + 3][r] = av.w;
            const float4 bv = *reinterpret_cast<const float4*>(
                W + (size_t)(col0 + r) * FDIM + k0 + c);
            Bs[c + 0][r] = bv.x; Bs[c + 1][r] = bv.y;
            Bs[c + 2][r] = bv.z; Bs[c + 3][r] = bv.w;
        }
        __syncthreads();
        #pragma unroll
        for (int k = 0; k < 32; ++k) {
            float a[4], b[4];
            #pragma unroll
            for (int i = 0; i < 4; ++i) a[i] = As[k][tm * 4 + i];
            #pragma unroll
            for (int j = 0; j < 4; ++j) b[j] = Bs[k][tn * 4 + j];
            #pragma unroll
            for (int i = 0; i < 4; ++i)
                #pragma unroll
                for (int j = 0; j < 4; ++j)
                    acc[i][j] += a[i] * b[j];
        }
        __syncthreads();
    }

    #pragma unroll
    for (int i = 0; i < 4; ++i) {
        const size_t ro = (size_t)(row0 + tm * 4 + i) * GE + col0 + tn * 4;
        #pragma unroll
        for (int j = 0; j < 4; ++j)
            L[ro + j] = acc[i][j] + bias[col0 + tn * 4 + j];
    }
}

// ---------------- per-(n,g) epilogue ----------------
// One wave handles 16 (n,g) pairs, all with the same g (rows strided by 1024).
// L aliases the cb output region: each (n,g) slice is read (into regs) then
// overwritten by exactly the owning wave, same per-lane addresses.
__global__ __launch_bounds__(256) void vq_rows_k(
    float* __restrict__ Lcb,                 // logits in, cb out (same region)
    const float* __restrict__ gumbel,
    const float* __restrict__ entries,
    float* __restrict__ out,                 // d_out base (quantized at 0)
    float* __restrict__ hard_acc,            // ws[0..640)
    float* __restrict__ soft_acc)            // ws[640..1280)
{
    const int tid  = threadIdx.x;
    const int lane = tid & 63;
    const int w    = blockIdx.x * 4 + (tid >> 6);   // 0..2047
    const int g    = w >> 10;                        // 0/1
    const int nb   = w & 1023;

    float racc[5] = {0.f, 0.f, 0.f, 0.f, 0.f};
    float hacc[5] = {0.f, 0.f, 0.f, 0.f, 0.f};

    for (int i = 0; i < 16; ++i) {
        const int n = nb + (i << 10);
        float* lrow = Lcb + (size_t)n * GE + g * EDIM;
        const float* grow = gumbel + ((size_t)n * 2 + g) * EDIM;

        float l[5], t[5];
        #pragma unroll
        for (int j = 0; j < 5; ++j) {
            const int e = lane + j * 64;
            l[j] = lrow[e];
            t[j] = (l[j] + grow[e]) * 0.5f;   // (logits+gumbel)/TAU, TAU=2
        }

        // local argmax (first-index tie-break: strict > with ascending e)
        float hv = l[0]; int hi = lane;
        float gv = t[0]; int gi = lane;
        #pragma unroll
        for (int j = 1; j < 5; ++j) {
            const int e = lane + j * 64;
            if (l[j] > hv) { hv = l[j]; hi = e; }
            if (t[j] > gv) { gv = t[j]; gi = e; }
        }
        // wave argmax reduce
        #pragma unroll
        for (int off = 32; off > 0; off >>= 1) {
            float ov = __shfl_xor(hv, off); int oi = __shfl_xor(hi, off);
            if (ov > hv || (ov == hv && oi < hi)) { hv = ov; hi = oi; }
            float ov2 = __shfl_xor(gv, off); int oi2 = __shfl_xor(gi, off);
            if (ov2 > gv || (ov2 == gv && oi2 < gi)) { gv = ov2; gi = oi2; }
        }

        // softmax exps + sums
        float eh[5], eg[5];
        float sh = 0.f, sg = 0.f;
        #pragma unroll
        for (int j = 0; j < 5; ++j) {
            eh[j] = expf(l[j] - hv);
            eg[j] = expf(t[j] - gv);
            sh += eh[j]; sg += eg[j];
        }
        #pragma unroll
        for (int off = 32; off > 0; off >>= 1) {
            sh += __shfl_xor(sh, off);
            sg += __shfl_xor(sg, off);
        }
        const float ish = 1.0f / sh;
        const float isg = 1.0f / sg;

        // accumulate soft probs + hard counts
        float a_part = 0.f;
        #pragma unroll
        for (int j = 0; j < 5; ++j) {
            const int e = lane + j * 64;
            racc[j] += eh[j] * ish;
            if (e == hi) hacc[j] += 1.0f;
            if (e == gi) a_part = eg[j] * isg;
        }
        #pragma unroll
        for (int off = 32; off > 0; off >>= 1) a_part += __shfl_xor(a_part, off);
        const float yv = (1.0f - a_part) + a_part;   // straight-through value at argmax

        // cb write (overwrites logits slice in place)
        #pragma unroll
        for (int j = 0; j < 5; ++j) {
            const int e = lane + j * 64;
            lrow[e] = (e == gi) ? yv : 0.0f;
        }

        // quantized write: yv * entries[g, gi, :]
        const float* ent = entries + ((size_t)(g * EDIM + gi)) * DDIM;
        float* qrow = out + (size_t)n * 768 + g * DDIM;
        #pragma unroll
        for (int jj = 0; jj < 6; ++jj) {
            const int d = lane + jj * 64;
            qrow[d] = yv * ent[d];
        }
    }

    #pragma unroll
    for (int j = 0; j < 5; ++j) {
        const int e = g * EDIM + lane + j * 64;
        atomicAdd(&hard_acc[e], hacc[j]);
        atomicAdd(&soft_acc[e], racc[j]);
    }
}

// ---------------- perplexities ----------------
__global__ void vq_final_k(const float* __restrict__ hard_acc,
                           const float* __restrict__ soft_acc,
                           float* __restrict__ out)
{
    const int lane = threadIdx.x & 63;
    float code = 0.f, prob = 0.f;
    for (int g = 0; g < 2; ++g) {
        float shh = 0.f, sss = 0.f;
        #pragma unroll
        for (int j = 0; j < 5; ++j) {
            const int e = g * EDIM + lane + j * 64;
            const float ph = hard_acc[e] * (1.0f / 16384.0f);
            const float ps = soft_acc[e] * (1.0f / 16384.0f);
            shh += ph * logf(ph + 1e-7f);
            sss += ps * logf(ps + 1e-7f);
        }
        #pragma unroll
        for (int off = 32; off > 0; off >>= 1) {
            shh += __shfl_xor(shh, off);
            sss += __shfl_xor(sss, off);
        }
        code += expf(-shh);
        prob += expf(-sss);
    }
    if (threadIdx.x == 0) {
        out[SCAL_OFF + 0] = code;
        out[SCAL_OFF + 1] = prob;
    }
}

extern "C" void kernel_launch(void* const* d_in, const int* in_sizes, int n_in,
                              void* d_out, int out_size, void* d_ws, size_t ws_size,
                              hipStream_t stream) {
    const float* x       = (const float*)d_in[0];
    const float* proj_w  = (const float*)d_in[1];
    const float* proj_b  = (const float*)d_in[2];
    const float* entries = (const float*)d_in[3];
    const float* gumbel  = (const float*)d_in[4];
    float* out = (float*)d_out;
    float* acc = (float*)d_ws;                 // 1280 floats
    float* logits = out + CB_OFF;              // stage logits in cb region

    hipLaunchKernelGGL(vq_init_k, dim3(5), dim3(256), 0, stream, acc);
    hipLaunchKernelGGL(gemm_logits_k, dim3(NROWS / 64, GE / 64), dim3(256), 0, stream,
                       x, proj_w, proj_b, logits);
    hipLaunchKernelGGL(vq_rows_k, dim3(512), dim3(256), 0, stream,
                       logits, gumbel, entries, out, acc, acc + GE);
    hipLaunchKernelGGL(vq_final_k, dim3(1), dim3(64), 0, stream,
                       acc, acc + GE, out);
}